// Round 7
// baseline (857.742 us; speedup 1.0000x reference)
//
#include <hip/hip_runtime.h>
#include <hip/hip_bf16.h>
#include <hip/hip_fp16.h>
#include <string.h>

typedef unsigned short u16;
typedef __attribute__((ext_vector_type(4))) short short4v;
typedef __attribute__((ext_vector_type(8))) short short8;
typedef __attribute__((ext_vector_type(4))) float floatx4;
typedef __attribute__((ext_vector_type(16))) float floatx16;

#define N_TOK 4096
#define D_DIM 256
#define H_HEAD 8

__device__ __forceinline__ u16 f2b(float f){
  __hip_bfloat16 h = __float2bfloat16(f);
  return *reinterpret_cast<u16*>(&h);
}
__device__ __forceinline__ float b2f(u16 u){
  union { unsigned u; float f; } c; c.u = ((unsigned)u) << 16; return c.f;
}
__device__ __forceinline__ float h2f(u16 u){
  __half h; *reinterpret_cast<u16*>(&h) = u; return __half2float(h);
}
__device__ __forceinline__ u16 f2h(float f){
  __half h = __float2half(f); return *reinterpret_cast<u16*>(&h);
}
__device__ __forceinline__ unsigned pk2bf(float a, float b){
  __hip_bfloat162 h = __float22bfloat162_rn(make_float2(a, b));
  return *reinterpret_cast<unsigned*>(&h);
}

__device__ __forceinline__ void glds16(const void* g, void* l){
  __builtin_amdgcn_global_load_lds(
      (const __attribute__((address_space(1))) unsigned int*)g,
      (__attribute__((address_space(3))) unsigned int*)l, 16, 0, 0);
}

// ---------------- fused prep: weight cvt + qkv bias concat ----------------
__global__ void fused_prep(const float* __restrict__ Wq, const float* __restrict__ Wk,
                           const float* __restrict__ Wv, const float* __restrict__ Wo,
                           const float* __restrict__ Wff,
                           const float* __restrict__ bq, const float* __restrict__ bk,
                           const float* __restrict__ bv,
                           u16* __restrict__ wqkv, u16* __restrict__ wo_b,
                           u16* __restrict__ wff_b, float* __restrict__ bqkv){
  int bid = blockIdx.x;
  if (bid == 1056){
    int t = threadIdx.x;
    for (int j = 0; j < 24; ++j){
      int idx = t + j*256;
      float v;
      if (idx < 2048) v = bq[idx];
      else if (idx < 4096) v = bk[idx - 2048];
      else v = bv[idx - 4096];
      bqkv[idx] = v;
    }
    return;
  }
  const float* src; u16* dst; int base;
  if      (bid < 256) { src = Wq;  dst = wqkv;            base = bid; }
  else if (bid < 512) { src = Wk;  dst = wqkv + 524288;   base = bid - 256; }
  else if (bid < 768) { src = Wv;  dst = wqkv + 1048576;  base = bid - 512; }
  else if (bid < 1024){ src = Wo;  dst = wo_b;            base = bid - 768; }
  else                { src = Wff; dst = wff_b;           base = bid - 1024; }
  int i = (base*256 + threadIdx.x)*8;
  float4 a = *(const float4*)(src + i);
  float4 b = *(const float4*)(src + i + 4);
  u16 u[8] = {f2b(a.x),f2b(a.y),f2b(a.z),f2b(a.w),f2b(b.x),f2b(b.y),f2b(b.z),f2b(b.w)};
  *(short8*)(dst + i) = *(short8*)u;
}

// ---------------- layernorm: fp32 in -> bf16 out ----------------
__global__ void ln_kernel(const float* __restrict__ x, const float* __restrict__ g,
                          const float* __restrict__ b, u16* __restrict__ out){
  const int row = blockIdx.x;
  const int t = threadIdx.x;
  float v = x[(size_t)row*D_DIM + t];
  float s = v, ss = v*v;
  #pragma unroll
  for (int off = 32; off > 0; off >>= 1){
    s  += __shfl_down(s,  off);
    ss += __shfl_down(ss, off);
  }
  __shared__ float ls[4], lss[4];
  const int w = t >> 6, lane = t & 63;
  if (lane == 0){ ls[w] = s; lss[w] = ss; }
  __syncthreads();
  if (t == 0){
    float S  = ls[0]+ls[1]+ls[2]+ls[3];
    float SS = lss[0]+lss[1]+lss[2]+lss[3];
    float mu = S * (1.0f/D_DIM);
    float var = SS * (1.0f/D_DIM) - mu*mu;
    ls[0] = mu; lss[0] = rsqrtf(var + 1e-5f);
  }
  __syncthreads();
  float mu = ls[0], rs = lss[0];
  out[(size_t)row*D_DIM + t] = f2b((v - mu)*rs*g[t] + b[t]);
}

// ---------------- ln_sum: x_out = p0+p1+bo+x ; LN2 -> bf16 ; also write x_out fp32 ----
__global__ void ln_sum(const float* __restrict__ p0, const float* __restrict__ p1,
                       const float* __restrict__ bo, const float* __restrict__ x,
                       const float* __restrict__ g, const float* __restrict__ b,
                       float* __restrict__ xout, u16* __restrict__ xln2){
  const int row = blockIdx.x;
  const int t = threadIdx.x;
  const size_t idx = (size_t)row*D_DIM + t;
  float v = p0[idx] + p1[idx] + bo[t] + x[idx];
  float s = v, ss = v*v;
  #pragma unroll
  for (int off = 32; off > 0; off >>= 1){
    s  += __shfl_down(s,  off);
    ss += __shfl_down(ss, off);
  }
  __shared__ float ls[4], lss[4];
  const int w = t >> 6, lane = t & 63;
  if (lane == 0){ ls[w] = s; lss[w] = ss; }
  __syncthreads();
  if (t == 0){
    float S  = ls[0]+ls[1]+ls[2]+ls[3];
    float SS = lss[0]+lss[1]+lss[2]+lss[3];
    float mu = S * (1.0f/D_DIM);
    float var = SS * (1.0f/D_DIM) - mu*mu;
    ls[0] = mu; lss[0] = rsqrtf(var + 1e-5f);
  }
  __syncthreads();
  float mu = ls[0], rs = lss[0];
  xout[idx] = v;
  xln2[idx] = f2b((v - mu)*rs*g[t] + b[t]);
}

// ---------------- biasW: (spatial+edge)*log2e fp16, masked=-inf, MFMA C-layout ----
__global__ void make_biasW(const float* __restrict__ sp, const float* __restrict__ ed,
                           const int* __restrict__ mask, u16* __restrict__ out){
  __shared__ u16 bh[32][64];
  const int tg = blockIdx.x, q32 = blockIdx.y;
  const int t = threadIdx.x;
  const float L2E = 1.4426950408889634f;
  const u16 NINF = 0xFC00;  // fp16 -inf
  {
    int ql = t>>3, kc = (t&7)*8;
    size_t off = (size_t)(q32*32 + ql)*N_TOK + tg*64 + kc;
    float4 s0 = *(const float4*)(sp + off);
    float4 s1 = *(const float4*)(sp + off + 4);
    float4 e0 = *(const float4*)(ed + off);
    float4 e1 = *(const float4*)(ed + off + 4);
    int mr = mask[q32*32 + ql];
    int4 m0 = *(const int4*)(mask + tg*64 + kc);
    int4 m1 = *(const int4*)(mask + tg*64 + kc + 4);
    bh[ql][kc+0] = (mr*m0.x)==0 ? NINF : f2h((s0.x+e0.x)*L2E);
    bh[ql][kc+1] = (mr*m0.y)==0 ? NINF : f2h((s0.y+e0.y)*L2E);
    bh[ql][kc+2] = (mr*m0.z)==0 ? NINF : f2h((s0.z+e0.z)*L2E);
    bh[ql][kc+3] = (mr*m0.w)==0 ? NINF : f2h((s0.w+e0.w)*L2E);
    bh[ql][kc+4] = (mr*m1.x)==0 ? NINF : f2h((s1.x+e1.x)*L2E);
    bh[ql][kc+5] = (mr*m1.y)==0 ? NINF : f2h((s1.y+e1.y)*L2E);
    bh[ql][kc+6] = (mr*m1.z)==0 ? NINF : f2h((s1.z+e1.z)*L2E);
    bh[ql][kc+7] = (mr*m1.w)==0 ? NINF : f2h((s1.w+e1.w)*L2E);
  }
  __syncthreads();
  int lane2 = t>>2, j0 = (t&3)*8;
  u16 tmp[8];
  #pragma unroll
  for (int jj = 0; jj < 8; ++jj){
    int j = j0 + jj;
    int nb = j>>4, reg = j&15;
    int kvl = nb*32 + (reg&3) + 8*(reg>>2) + 4*(lane2>>5);
    tmp[jj] = bh[lane2&31][kvl];
  }
  u16* dst = out + (((size_t)q32*64 + tg)*64 + lane2)*32 + j0;
  *(short8*)dst = *(short8*)tmp;
}

// ---------------- bf16 GEMM, C = A * B^T (+bias, +resid), lda/ldb pitches ----
// MODE 0: QKV — out bf16; col<2048 scaled by (1/16)*log2e; cols>=4096 (V)
//         written TRANSPOSED to vt[h][e][n] (passed via `resid`).
// MODE 2: out fp32 = acc + bias[col] + resid[idx].
// MODE 3: split-K partial, out fp32 raw at Cout + z*N*D, k-offset z*K.
template<int BM, int BN, int MODE>
__launch_bounds__(256, 2)
__global__ void gemm_bt(const u16* __restrict__ A, const u16* __restrict__ B, int K,
                        int lda, int ldb,
                        const float* __restrict__ bias, const float* __restrict__ resid,
                        void* __restrict__ Cout){
  constexpr int BK = 32;
  constexpr int WM = BM/2, WN = BN/2, FM = WM/16, FN = WN/16;
  constexpr int CApW = BM/64;
  constexpr int CBpW = BN/64;
  __shared__ u16 As[BM*BK];
  __shared__ u16 Bs[BN*BK];
  const int tid = threadIdx.x, w = tid>>6, lane = tid&63;
  const int quad = lane>>4, c16 = lane&15;
  const int wr = w>>1, wc = w&1;
  const int rowT = blockIdx.y*BM, colT = blockIdx.x*BN;
  const int lr = lane>>2;
  const int spos = lane&3;
  const int koff = (MODE == 3) ? (int)blockIdx.z*K : 0;

  floatx4 acc[FM][FN] = {};

  for (int k0 = 0; k0 < K; k0 += BK){
    #pragma unroll
    for (int i = 0; i < CApW; ++i){
      int ch = w*CApW + i;
      int row = ch*16 + lr;
      int gch = spos ^ ((row>>1)&3);
      const u16* g = A + (size_t)(rowT + row)*lda + koff + k0 + gch*8;
      glds16(g, As + ch*512);
    }
    #pragma unroll
    for (int i = 0; i < CBpW; ++i){
      int ch = w*CBpW + i;
      int row = ch*16 + lr;
      int gch = spos ^ ((row>>1)&3);
      const u16* g = B + (size_t)(colT + row)*ldb + koff + k0 + gch*8;
      glds16(g, Bs + ch*512);
    }
    __syncthreads();
    short8 af[FM], bf[FN];
    #pragma unroll
    for (int i = 0; i < FM; ++i){
      int row = wr*WM + i*16 + c16;
      int slot = quad ^ ((row>>1)&3);
      af[i] = *(const short8*)&As[row*BK + slot*8];
    }
    #pragma unroll
    for (int j = 0; j < FN; ++j){
      int row = wc*WN + j*16 + c16;
      int slot = quad ^ ((row>>1)&3);
      bf[j] = *(const short8*)&Bs[row*BK + slot*8];
    }
    #pragma unroll
    for (int i = 0; i < FM; ++i)
      #pragma unroll
      for (int j = 0; j < FN; ++j)
        acc[i][j] = __builtin_amdgcn_mfma_f32_16x16x32_bf16(af[i], bf[j], acc[i][j], 0, 0, 0);
    __syncthreads();
  }

  if (MODE == 0){
    u16* o = (u16*)Cout;
    u16* vtp = (u16*)(size_t)resid;   // vt[h][e][n] destination for V cols
    #pragma unroll
    for (int i = 0; i < FM; ++i)
      #pragma unroll
      for (int j = 0; j < FN; ++j){
        int col = colT + wc*WN + j*16 + c16;
        float bv = bias[col];
        if (col < 4096){
          float sc = (col < 2048) ? 0.09016994374947424f : 1.0f;
          size_t obase = (size_t)(col>>8)*((size_t)N_TOK*D_DIM) + (col & 255);
          #pragma unroll
          for (int r = 0; r < 4; ++r){
            int row = rowT + wr*WM + i*16 + quad*4 + r;
            o[obase + (size_t)row*D_DIM] = f2b((acc[i][j][r] + bv)*sc);
          }
        } else {
          // V column -> vt[(col-4096)][n], 4 consecutive n = one 8B store
          int row0 = rowT + wr*WM + i*16 + quad*4;
          u16 o4[4];
          #pragma unroll
          for (int r = 0; r < 4; ++r) o4[r] = f2b(acc[i][j][r] + bv);
          *(short4v*)(vtp + (size_t)(col - 4096)*N_TOK + row0) = *(short4v*)o4;
        }
      }
  } else if (MODE == 2){
    float* o = (float*)Cout;
    #pragma unroll
    for (int i = 0; i < FM; ++i)
      #pragma unroll
      for (int j = 0; j < FN; ++j){
        int col = colT + wc*WN + j*16 + c16;
        float bv = bias[col];
        #pragma unroll
        for (int r = 0; r < 4; ++r){
          int row = rowT + wr*WM + i*16 + quad*4 + r;
          size_t idx = (size_t)row*D_DIM + col;
          o[idx] = acc[i][j][r] + bv + resid[idx];
        }
      }
  } else {
    float* o = (float*)Cout + (size_t)blockIdx.z*((size_t)N_TOK*D_DIM);
    #pragma unroll
    for (int i = 0; i < FM; ++i)
      #pragma unroll
      for (int j = 0; j < FN; ++j){
        int col = colT + wc*WN + j*16 + c16;
        #pragma unroll
        for (int r = 0; r < 4; ++r){
          int row = rowT + wr*WM + i*16 + quad*4 + r;
          o[(size_t)row*D_DIM + col] = acc[i][j][r];
        }
      }
  }
}

// ---------------- flash attention: V read direct from global (L2-hot) ----------------
// R5 analysis: LDS pipe ~60% busy (256 ds_read_b128/tile) was the top-loaded
// unit; V reads (64/tile) + Vs staging are removable because vt[h][e][n] is
// already B-operand-oriented and XCD-L2-resident (Common-mistake #7 / m169).
// LDS now Ks 32K + Ps 16K = 48 KB -> TWO blocks/CU (96 KB LDS, 16 waves x
// 128 VGPR = full budget). __launch_bounds__(512,4) pins VGPR<=128.
// Wave roles, barriers, swizzles identical to the proven R1/R5 structure.
__launch_bounds__(512, 4)
__global__ void attn_kernel(const u16* __restrict__ Q, const u16* __restrict__ Kg,
                            const u16* __restrict__ Vt, const u16* __restrict__ biasW,
                            u16* __restrict__ cat0, u16* __restrict__ cat1,
                            float* __restrict__ lsum4){
  extern __shared__ __align__(16) u16 lds[];
  u16* Ks = lds;           // [64 kv][256 e] chunk-swizzled (32 KB)
  u16* Ps = lds + 16384;   // [128 q][64 kv] chunk-swizzled (16 KB)
  const int bid = blockIdx.x;
  const int swz = (bid & 7)*64 + (bid >> 3);     // XCD-aware bijective remap
  const int bx = swz & 31, h = (swz >> 5) & 7, spl = swz >> 8;
  const int tid = threadIdx.x, w = tid>>6, lane = tid&63;
  const int hi = lane>>5, l31 = lane&31;
  const int qg = w>>1, kvh = w&1;   // S-phase role
  const int qh = w&1, ev = w>>1;    // PV-phase role
  const int qbase = bx*128;
  const size_t hoff = (size_t)h*N_TOK*D_DIM;
  u16* cs = spl ? cat1 : cat0;

  // Q B-frags (S-phase)
  short8 qf[16];
  {
    const u16* qp = Q + hoff + (size_t)(qbase + qg*32 + l31)*D_DIM + hi*8;
    #pragma unroll
    for (int ks = 0; ks < 16; ++ks) qf[ks] = *(const short8*)(qp + ks*16);
  }

  floatx16 o00 = {}, o01 = {}, o10 = {}, o11 = {};  // [qs][es]
  float l_lane = 0.f;

  const u16* Kb0 = Kg + hoff + (size_t)spl*2048*D_DIM;
  const u16* Vb0 = Vt + hoff + spl*2048;            // vt[h][e][n] slice
  const u16* bWb = biasW + ((((size_t)(bx*4 + qg))*64 + spl*32)*64 + lane)*32 + kvh*16;
  // per-lane V row bases (PV): rows ev*64 + l31 and +32
  const u16* Vr0 = Vb0 + (size_t)(ev*64 +      l31)*N_TOK;
  const u16* Vr1 = Vb0 + (size_t)(ev*64 + 32 + l31)*N_TOK;

  // prologue: bias(0) + stage K tile 0
  short8 bv0 = *(const short8*)(bWb);
  short8 bv1 = *(const short8*)(bWb + 8);
  {
    #pragma unroll
    for (int i = 0; i < 4; ++i){
      int ch = w*4 + i;
      int row = ch*2 + hi;
      int gch = l31 ^ (row&7);
      glds16(Kb0 + (size_t)row*D_DIM + gch*8, Ks + ch*512);
    }
  }
  __syncthreads();

  for (int t = 0; t < 32; ++t){
    const int tn = (t + 1) & 31;

    // ---- S-phase ----
    floatx16 sa = {}, sb = {};
    const int krow = kvh*32 + l31;
    __builtin_amdgcn_s_setprio(1);
    #pragma unroll
    for (int ks = 0; ks < 16; ++ks){
      int slot = (2*ks + hi) ^ (l31&7);
      short8 ka = *(const short8*)&Ks[krow*256 + slot*8];
      if (ks & 1) sb = __builtin_amdgcn_mfma_f32_32x32x16_bf16(ka, qf[ks], sb, 0, 0, 0);
      else        sa = __builtin_amdgcn_mfma_f32_32x32x16_bf16(ka, qf[ks], sa, 0, 0, 0);
    }
    __builtin_amdgcn_s_setprio(0);

    // ---- softmax: p = exp2(s + bias)  (scale folded into Q, no max constant) ----
    {
      const int q = qg*32 + l31;
      #pragma unroll
      for (int g = 0; g < 4; ++g){
        u16 b0 = (g < 2) ? ((u16*)&bv0)[4*g+0] : ((u16*)&bv1)[4*(g-2)+0];
        u16 b1 = (g < 2) ? ((u16*)&bv0)[4*g+1] : ((u16*)&bv1)[4*(g-2)+1];
        u16 b2 = (g < 2) ? ((u16*)&bv0)[4*g+2] : ((u16*)&bv1)[4*(g-2)+2];
        u16 b3 = (g < 2) ? ((u16*)&bv0)[4*g+3] : ((u16*)&bv1)[4*(g-2)+3];
        float p0 = exp2f(sa[4*g+0] + sb[4*g+0] + h2f(b0));
        float p1 = exp2f(sa[4*g+1] + sb[4*g+1] + h2f(b1));
        float p2 = exp2f(sa[4*g+2] + sb[4*g+2] + h2f(b2));
        float p3 = exp2f(sa[4*g+3] + sb[4*g+3] + h2f(b3));
        l_lane += (p0 + p1) + (p2 + p3);
        uint2 pw;
        pw.x = pk2bf(p0, p1);
        pw.y = pk2bf(p2, p3);
        int slot = (kvh*4 + g) ^ (l31&7);
        *(uint2*)&Ps[q*64 + slot*8 + hi*4] = pw;
      }
    }
    __syncthreads();   // barrier 1: P visible, Ks reads done

    // stage K(t+1) + prefetch bias(t+1)
    {
      const u16* Kb = Kb0 + (size_t)tn*64*D_DIM;
      #pragma unroll
      for (int i = 0; i < 4; ++i){
        int ch = w*4 + i;
        int row = ch*2 + hi;
        int gch = l31 ^ (row&7);
        glds16(Kb + (size_t)row*D_DIM + gch*8, Ks + ch*512);
      }
      const u16* bW = bWb + (size_t)tn*64*32;
      bv0 = *(const short8*)(bW);
      bv1 = *(const short8*)(bW + 8);
    }

    // ---- PV-phase: O[q][e], V read direct from global vt (L2-hot) ----
    __builtin_amdgcn_s_setprio(1);
    #pragma unroll
    for (int ks2 = 0; ks2 < 4; ++ks2){
      int cA = ks2*2 + hi;
      int sl = cA ^ (l31&7);
      short8 pf0 = *(const short8*)&Ps[(qh*64 +      l31)*64 + sl*8];
      short8 pf1 = *(const short8*)&Ps[(qh*64 + 32 + l31)*64 + sl*8];
      short8 vf0 = *(const short8*)(Vr0 + t*64 + cA*8);
      short8 vf1 = *(const short8*)(Vr1 + t*64 + cA*8);
      o00 = __builtin_amdgcn_mfma_f32_32x32x16_bf16(pf0, vf0, o00, 0, 0, 0);
      o01 = __builtin_amdgcn_mfma_f32_32x32x16_bf16(pf0, vf1, o01, 0, 0, 0);
      o10 = __builtin_amdgcn_mfma_f32_32x32x16_bf16(pf1, vf0, o10, 0, 0, 0);
      o11 = __builtin_amdgcn_mfma_f32_32x32x16_bf16(pf1, vf1, o11, 0, 0, 0);
    }
    __builtin_amdgcn_s_setprio(0);
    __syncthreads();   // barrier 2: Ps reads done, K(t+1) drained
  }

  // ---- epilogue ----
  l_lane += __shfl_xor(l_lane, 32, 64);
  if (hi == 0)
    lsum4[(((size_t)spl*2 + kvh)*H_HEAD + h)*N_TOK + qbase + qg*32 + l31] = l_lane;

  #pragma unroll
  for (int reg = 0; reg < 16; ++reg){
    int qr = (reg&3) + 8*(reg>>2) + 4*hi;
    int q0 = qbase + qh*64 + qr;
    size_t c0 = (size_t)q0*(H_HEAD*D_DIM) + h*D_DIM + ev*64 + l31;
    size_t c1 = (size_t)(q0+32)*(H_HEAD*D_DIM) + h*D_DIM + ev*64 + l31;
    cs[c0]      = f2b(o00[reg]);
    cs[c0 + 32] = f2b(o01[reg]);
    cs[c1]      = f2b(o10[reg]);
    cs[c1 + 32] = f2b(o11[reg]);
  }
}

// ---------------- combine2: cat = (c0+c1) * inv_l[q,h], elementwise ----------------
__global__ void combine2(const u16* __restrict__ c0, const u16* __restrict__ c1,
                         const float* __restrict__ lsum4, u16* __restrict__ cat){
  const int q = blockIdx.x;
  const int t = threadIdx.x;
  const int col = t*8;
  const int h = t >> 5;
  float l = 0.f;
  #pragma unroll
  for (int s = 0; s < 4; ++s)
    l += lsum4[((size_t)s*H_HEAD + h)*N_TOK + q];
  float inv = (l > 0.f) ? 1.0f/l : 0.f;
  size_t base = (size_t)q*(H_HEAD*D_DIM) + col;
  short8 a = *(const short8*)(c0 + base);
  short8 b = *(const short8*)(c1 + base);
  u16 o[8];
  #pragma unroll
  for (int i = 0; i < 8; ++i)
    o[i] = f2b((b2f(((u16*)&a)[i]) + b2f(((u16*)&b)[i]))*inv);
  *(short8*)(cat + base) = *(short8*)o;
}

// ---------------- launch ----------------
extern "C" void kernel_launch(void* const* d_in, const int* in_sizes, int n_in,
                              void* d_out, int out_size, void* d_ws, size_t ws_size,
                              hipStream_t stream){
  const float* x    = (const float*)d_in[0];
  const int*   mask = (const int*)  d_in[1];
  const float* sp   = (const float*)d_in[2];
  const float* ed   = (const float*)d_in[3];
  const float* g1   = (const float*)d_in[4];
  const float* b1   = (const float*)d_in[5];
  const float* Wq   = (const float*)d_in[6];
  const float* bq   = (const float*)d_in[7];
  const float* Wk   = (const float*)d_in[8];
  const float* bk   = (const float*)d_in[9];
  const float* Wv   = (const float*)d_in[10];
  const float* bv   = (const float*)d_in[11];
  const float* Wo   = (const float*)d_in[12];
  const float* bo   = (const float*)d_in[13];
  const float* g2   = (const float*)d_in[14];
  const float* b2   = (const float*)d_in[15];
  const float* Wff  = (const float*)d_in[16];
  const float* bff  = (const float*)d_in[17];
  float* out = (float*)d_out;
  char* ws = (char*)d_ws;

  constexpr size_t MB = 1ull<<20;
  u16*   wqkv   = (u16*)  (ws + 0);                 // 3 MB
  u16*   wo_b   = (u16*)  (ws + 3*MB);              // 1 MB
  u16*   wff_b  = (u16*)  (ws + 4*MB);              // 128 KB
  float* bqkv   = (float*)(ws + 4*MB + 256*1024);   // 24 KB
  u16*   xln    = (u16*)  (ws + 4*MB + 512*1024);   // 2 MB
  float* lsum4  = (float*)(ws + 6*MB + 512*1024);   // 512 KB
  u16*   qkv    = (u16*)  (ws + 7*MB);              // 48 MB: Q@7, K@23 (V slab unused)
  u16*   vt     = (u16*)  (ws + 55*MB);             // 16 MB (written by QKV GEMM)
  u16*   biasW  = (u16*)  (ws + 71*MB);             // 32 MB
  u16*   cat0   = (u16*)  (ws + 39*MB);             // 16 MB (overlays unused V slab)
  u16*   cat1   = (u16*)  (ws + 103*MB);            // 16 MB
  u16*   cat    = (u16*)  (ws + 7*MB);              // 16 MB (overlays dead Q)
  float* pK     = (float*)(ws + 23*MB);             // 8 MB  (overlays dead K)
  float* xout   = (float*)(ws + 31*MB);             // 4 MB
  u16*   xln2   = (u16*)  (ws + 35*MB);             // 2 MB
  const size_t TS = (size_t)H_HEAD*N_TOK*D_DIM;

  // weights -> bf16, qkv bias concat
  fused_prep<<<1057, 256, 0, stream>>>(Wq, Wk, Wv, Wo, Wff, bq, bk, bv,
                                       wqkv, wo_b, wff_b, bqkv);
  // LN1
  ln_kernel<<<N_TOK, 256, 0, stream>>>(x, g1, b1, xln);

  // QKV projection (V cols written transposed straight into vt)
  gemm_bt<128,128,0><<<dim3(48, 32), 256, 0, stream>>>(xln, wqkv, 256, 256, 256,
                                                       bqkv, (const float*)vt, qkv);

  // swizzled combined bias (no constant offset, masked = -inf)
  make_biasW<<<dim3(64, 128), 256, 0, stream>>>(sp, ed, mask, biasW);

  // flash attention (flat 512-block grid, XCD-swizzled, 48 KB LDS, 2 blocks/CU)
  hipFuncSetAttribute((const void*)attn_kernel,
                      hipFuncAttributeMaxDynamicSharedMemorySize, 49152);
  attn_kernel<<<dim3(512), 512, 49152, stream>>>(qkv, qkv + TS, vt, biasW,
                                                 cat0, cat1, lsum4);

  // combine splits + normalize (elementwise)
  combine2<<<N_TOK, 256, 0, stream>>>(cat0, cat1, lsum4, cat);

  // output projection, split-K=2, raw fp32 partials
  gemm_bt<64,64,3><<<dim3(4, 64, 2), 256, 0, stream>>>(cat, wo_b, 1024, 2048, 2048,
                                                       nullptr, nullptr, pK);

  // sum partials + bo + x residual + LN2
  ln_sum<<<N_TOK, 256, 0, stream>>>(pK, pK + (size_t)N_TOK*D_DIM, bo, x, g2, b2,
                                    xout, xln2);

  // FF + residual
  gemm_bt<64,64,2><<<dim3(4, 64), 256, 0, stream>>>(xln2, wff_b, 256, 256, 256,
                                                    bff, xout, out);
}

// Round 11
// 419.680 us; speedup vs baseline: 2.0438x; 2.0438x over previous
//
#include <hip/hip_runtime.h>
#include <hip/hip_bf16.h>
#include <hip/hip_fp16.h>
#include <string.h>

typedef unsigned short u16;
typedef __attribute__((ext_vector_type(4))) short short4v;
typedef __attribute__((ext_vector_type(8))) short short8;
typedef __attribute__((ext_vector_type(4))) float floatx4;
typedef __attribute__((ext_vector_type(16))) float floatx16;

#define N_TOK 4096
#define D_DIM 256
#define H_HEAD 8

__device__ __forceinline__ u16 f2b(float f){
  __hip_bfloat16 h = __float2bfloat16(f);
  return *reinterpret_cast<u16*>(&h);
}
__device__ __forceinline__ float b2f(u16 u){
  union { unsigned u; float f; } c; c.u = ((unsigned)u) << 16; return c.f;
}
__device__ __forceinline__ float h2f(u16 u){
  __half h; *reinterpret_cast<u16*>(&h) = u; return __half2float(h);
}
__device__ __forceinline__ u16 f2h(float f){
  __half h = __float2half(f); return *reinterpret_cast<u16*>(&h);
}
__device__ __forceinline__ unsigned pk2bf(float a, float b){
  __hip_bfloat162 h = __float22bfloat162_rn(make_float2(a, b));
  return *reinterpret_cast<unsigned*>(&h);
}

__device__ __forceinline__ void glds16(const void* g, void* l){
  __builtin_amdgcn_global_load_lds(
      (const __attribute__((address_space(1))) unsigned int*)g,
      (__attribute__((address_space(3))) unsigned int*)l, 16, 0, 0);
}

// ---------------- fused prep: weight cvt + qkv bias concat ----------------
__global__ void fused_prep(const float* __restrict__ Wq, const float* __restrict__ Wk,
                           const float* __restrict__ Wv, const float* __restrict__ Wo,
                           const float* __restrict__ Wff,
                           const float* __restrict__ bq, const float* __restrict__ bk,
                           const float* __restrict__ bv,
                           u16* __restrict__ wqkv, u16* __restrict__ wo_b,
                           u16* __restrict__ wff_b, float* __restrict__ bqkv){
  int bid = blockIdx.x;
  if (bid == 1056){
    int t = threadIdx.x;
    for (int j = 0; j < 24; ++j){
      int idx = t + j*256;
      float v;
      if (idx < 2048) v = bq[idx];
      else if (idx < 4096) v = bk[idx - 2048];
      else v = bv[idx - 4096];
      bqkv[idx] = v;
    }
    return;
  }
  const float* src; u16* dst; int base;
  if      (bid < 256) { src = Wq;  dst = wqkv;            base = bid; }
  else if (bid < 512) { src = Wk;  dst = wqkv + 524288;   base = bid - 256; }
  else if (bid < 768) { src = Wv;  dst = wqkv + 1048576;  base = bid - 512; }
  else if (bid < 1024){ src = Wo;  dst = wo_b;            base = bid - 768; }
  else                { src = Wff; dst = wff_b;           base = bid - 1024; }
  int i = (base*256 + threadIdx.x)*8;
  float4 a = *(const float4*)(src + i);
  float4 b = *(const float4*)(src + i + 4);
  u16 u[8] = {f2b(a.x),f2b(a.y),f2b(a.z),f2b(a.w),f2b(b.x),f2b(b.y),f2b(b.z),f2b(b.w)};
  *(short8*)(dst + i) = *(short8*)u;
}

// ---------------- layernorm: fp32 in -> bf16 out ----------------
__global__ void ln_kernel(const float* __restrict__ x, const float* __restrict__ g,
                          const float* __restrict__ b, u16* __restrict__ out){
  const int row = blockIdx.x;
  const int t = threadIdx.x;
  float v = x[(size_t)row*D_DIM + t];
  float s = v, ss = v*v;
  #pragma unroll
  for (int off = 32; off > 0; off >>= 1){
    s  += __shfl_down(s,  off);
    ss += __shfl_down(ss, off);
  }
  __shared__ float ls[4], lss[4];
  const int w = t >> 6, lane = t & 63;
  if (lane == 0){ ls[w] = s; lss[w] = ss; }
  __syncthreads();
  if (t == 0){
    float S  = ls[0]+ls[1]+ls[2]+ls[3];
    float SS = lss[0]+lss[1]+lss[2]+lss[3];
    float mu = S * (1.0f/D_DIM);
    float var = SS * (1.0f/D_DIM) - mu*mu;
    ls[0] = mu; lss[0] = rsqrtf(var + 1e-5f);
  }
  __syncthreads();
  float mu = ls[0], rs = lss[0];
  out[(size_t)row*D_DIM + t] = f2b((v - mu)*rs*g[t] + b[t]);
}

// ---------------- ln_sum: x_out = p0+p1+bo+x ; LN2 -> bf16 ; also write x_out fp32 ----
__global__ void ln_sum(const float* __restrict__ p0, const float* __restrict__ p1,
                       const float* __restrict__ bo, const float* __restrict__ x,
                       const float* __restrict__ g, const float* __restrict__ b,
                       float* __restrict__ xout, u16* __restrict__ xln2){
  const int row = blockIdx.x;
  const int t = threadIdx.x;
  const size_t idx = (size_t)row*D_DIM + t;
  float v = p0[idx] + p1[idx] + bo[t] + x[idx];
  float s = v, ss = v*v;
  #pragma unroll
  for (int off = 32; off > 0; off >>= 1){
    s  += __shfl_down(s,  off);
    ss += __shfl_down(ss, off);
  }
  __shared__ float ls[4], lss[4];
  const int w = t >> 6, lane = t & 63;
  if (lane == 0){ ls[w] = s; lss[w] = ss; }
  __syncthreads();
  if (t == 0){
    float S  = ls[0]+ls[1]+ls[2]+ls[3];
    float SS = lss[0]+lss[1]+lss[2]+lss[3];
    float mu = S * (1.0f/D_DIM);
    float var = SS * (1.0f/D_DIM) - mu*mu;
    ls[0] = mu; lss[0] = rsqrtf(var + 1e-5f);
  }
  __syncthreads();
  float mu = ls[0], rs = lss[0];
  xout[idx] = v;
  xln2[idx] = f2b((v - mu)*rs*g[t] + b[t]);
}

// ---------------- biasW: (spatial+edge)*log2e fp16, masked=-inf, MFMA C-layout ----
__global__ void make_biasW(const float* __restrict__ sp, const float* __restrict__ ed,
                           const int* __restrict__ mask, u16* __restrict__ out){
  __shared__ u16 bh[32][64];
  const int tg = blockIdx.x, q32 = blockIdx.y;
  const int t = threadIdx.x;
  const float L2E = 1.4426950408889634f;
  const u16 NINF = 0xFC00;  // fp16 -inf
  {
    int ql = t>>3, kc = (t&7)*8;
    size_t off = (size_t)(q32*32 + ql)*N_TOK + tg*64 + kc;
    float4 s0 = *(const float4*)(sp + off);
    float4 s1 = *(const float4*)(sp + off + 4);
    float4 e0 = *(const float4*)(ed + off);
    float4 e1 = *(const float4*)(ed + off + 4);
    int mr = mask[q32*32 + ql];
    int4 m0 = *(const int4*)(mask + tg*64 + kc);
    int4 m1 = *(const int4*)(mask + tg*64 + kc + 4);
    bh[ql][kc+0] = (mr*m0.x)==0 ? NINF : f2h((s0.x+e0.x)*L2E);
    bh[ql][kc+1] = (mr*m0.y)==0 ? NINF : f2h((s0.y+e0.y)*L2E);
    bh[ql][kc+2] = (mr*m0.z)==0 ? NINF : f2h((s0.z+e0.z)*L2E);
    bh[ql][kc+3] = (mr*m0.w)==0 ? NINF : f2h((s0.w+e0.w)*L2E);
    bh[ql][kc+4] = (mr*m1.x)==0 ? NINF : f2h((s1.x+e1.x)*L2E);
    bh[ql][kc+5] = (mr*m1.y)==0 ? NINF : f2h((s1.y+e1.y)*L2E);
    bh[ql][kc+6] = (mr*m1.z)==0 ? NINF : f2h((s1.z+e1.z)*L2E);
    bh[ql][kc+7] = (mr*m1.w)==0 ? NINF : f2h((s1.w+e1.w)*L2E);
  }
  __syncthreads();
  int lane2 = t>>2, j0 = (t&3)*8;
  u16 tmp[8];
  #pragma unroll
  for (int jj = 0; jj < 8; ++jj){
    int j = j0 + jj;
    int nb = j>>4, reg = j&15;
    int kvl = nb*32 + (reg&3) + 8*(reg>>2) + 4*(lane2>>5);
    tmp[jj] = bh[lane2&31][kvl];
  }
  u16* dst = out + (((size_t)q32*64 + tg)*64 + lane2)*32 + j0;
  *(short8*)dst = *(short8*)tmp;
}

// ---------------- bf16 GEMM, C = A * B^T (+bias, +resid), lda/ldb pitches ----
// MODE 0: QKV — out bf16; col<2048 scaled by (1/16)*log2e; cols>=4096 (V)
//         written TRANSPOSED to vt[h][e][n] (passed via `resid`).
// MODE 2: out fp32 = acc + bias[col] + resid[idx].
// MODE 3: split-K partial, out fp32 raw at Cout + z*N*D, k-offset z*K.
template<int BM, int BN, int MODE>
__launch_bounds__(256, 2)
__global__ void gemm_bt(const u16* __restrict__ A, const u16* __restrict__ B, int K,
                        int lda, int ldb,
                        const float* __restrict__ bias, const float* __restrict__ resid,
                        void* __restrict__ Cout){
  constexpr int BK = 32;
  constexpr int WM = BM/2, WN = BN/2, FM = WM/16, FN = WN/16;
  constexpr int CApW = BM/64;
  constexpr int CBpW = BN/64;
  __shared__ u16 As[BM*BK];
  __shared__ u16 Bs[BN*BK];
  const int tid = threadIdx.x, w = tid>>6, lane = tid&63;
  const int quad = lane>>4, c16 = lane&15;
  const int wr = w>>1, wc = w&1;
  const int rowT = blockIdx.y*BM, colT = blockIdx.x*BN;
  const int lr = lane>>2;
  const int spos = lane&3;
  const int koff = (MODE == 3) ? (int)blockIdx.z*K : 0;

  floatx4 acc[FM][FN] = {};

  for (int k0 = 0; k0 < K; k0 += BK){
    #pragma unroll
    for (int i = 0; i < CApW; ++i){
      int ch = w*CApW + i;
      int row = ch*16 + lr;
      int gch = spos ^ ((row>>1)&3);
      const u16* g = A + (size_t)(rowT + row)*lda + koff + k0 + gch*8;
      glds16(g, As + ch*512);
    }
    #pragma unroll
    for (int i = 0; i < CBpW; ++i){
      int ch = w*CBpW + i;
      int row = ch*16 + lr;
      int gch = spos ^ ((row>>1)&3);
      const u16* g = B + (size_t)(colT + row)*ldb + koff + k0 + gch*8;
      glds16(g, Bs + ch*512);
    }
    __syncthreads();
    short8 af[FM], bf[FN];
    #pragma unroll
    for (int i = 0; i < FM; ++i){
      int row = wr*WM + i*16 + c16;
      int slot = quad ^ ((row>>1)&3);
      af[i] = *(const short8*)&As[row*BK + slot*8];
    }
    #pragma unroll
    for (int j = 0; j < FN; ++j){
      int row = wc*WN + j*16 + c16;
      int slot = quad ^ ((row>>1)&3);
      bf[j] = *(const short8*)&Bs[row*BK + slot*8];
    }
    #pragma unroll
    for (int i = 0; i < FM; ++i)
      #pragma unroll
      for (int j = 0; j < FN; ++j)
        acc[i][j] = __builtin_amdgcn_mfma_f32_16x16x32_bf16(af[i], bf[j], acc[i][j], 0, 0, 0);
    __syncthreads();
  }

  if (MODE == 0){
    u16* o = (u16*)Cout;
    u16* vtp = (u16*)(size_t)resid;   // vt[h][e][n] destination for V cols
    #pragma unroll
    for (int i = 0; i < FM; ++i)
      #pragma unroll
      for (int j = 0; j < FN; ++j){
        int col = colT + wc*WN + j*16 + c16;
        float bv = bias[col];
        if (col < 4096){
          float sc = (col < 2048) ? 0.09016994374947424f : 1.0f;
          size_t obase = (size_t)(col>>8)*((size_t)N_TOK*D_DIM) + (col & 255);
          #pragma unroll
          for (int r = 0; r < 4; ++r){
            int row = rowT + wr*WM + i*16 + quad*4 + r;
            o[obase + (size_t)row*D_DIM] = f2b((acc[i][j][r] + bv)*sc);
          }
        } else {
          // V column -> vt[(col-4096)][n], 4 consecutive n = one 8B store
          int row0 = rowT + wr*WM + i*16 + quad*4;
          u16 o4[4];
          #pragma unroll
          for (int r = 0; r < 4; ++r) o4[r] = f2b(acc[i][j][r] + bv);
          *(short4v*)(vtp + (size_t)(col - 4096)*N_TOK + row0) = *(short4v*)o4;
        }
      }
  } else if (MODE == 2){
    float* o = (float*)Cout;
    #pragma unroll
    for (int i = 0; i < FM; ++i)
      #pragma unroll
      for (int j = 0; j < FN; ++j){
        int col = colT + wc*WN + j*16 + c16;
        float bv = bias[col];
        #pragma unroll
        for (int r = 0; r < 4; ++r){
          int row = rowT + wr*WM + i*16 + quad*4 + r;
          size_t idx = (size_t)row*D_DIM + col;
          o[idx] = acc[i][j][r] + bv + resid[idx];
        }
      }
  } else {
    float* o = (float*)Cout + (size_t)blockIdx.z*((size_t)N_TOK*D_DIM);
    #pragma unroll
    for (int i = 0; i < FM; ++i)
      #pragma unroll
      for (int j = 0; j < FN; ++j){
        int col = colT + wc*WN + j*16 + c16;
        #pragma unroll
        for (int r = 0; r < 4; ++r){
          int row = rowT + wr*WM + i*16 + quad*4 + r;
          o[(size_t)row*D_DIM + col] = acc[i][j][r];
        }
      }
  }
}

// ---------------- flash attention, phase-split, O written in cat orientation ----
// R7-R10: PRIOR-SESSION baseline structure (422.6 µs session): grid
// dim3(32,8,2), NO XCD swizzle, NO setprio — A/B subtraction test for the
// two R0 additions (never isolated; this session measured 452+ with them).
// V staged from fused vt (R5 win kept). R7 proved V must be LDS-staged:
// direct per-lane row-gather from vt was 10x HBM fetch and 3x slower.
// S-phase: wave (qg=w>>1, kvh=w&1): 32kv x 32q quarter of S^T -> softmax -> P^T LDS.
// PV-phase: wave (qh=w&1, ev=w>>1): O[q 64][e 64] = P[q][kv] * V^T[kv][e].
__launch_bounds__(512, 2)
__global__ void attn_kernel(const u16* __restrict__ Q, const u16* __restrict__ Kg,
                            const u16* __restrict__ Vt, const u16* __restrict__ biasW,
                            u16* __restrict__ cat0, u16* __restrict__ cat1,
                            float* __restrict__ lsum4){
  extern __shared__ __align__(16) u16 lds[];
  u16* Ks = lds;           // [64 kv][256 e] chunk-swizzled (32 KB)
  u16* Vs = lds + 16384;   // [256 e][64 kv] chunk-swizzled (32 KB)
  u16* Ps = lds + 32768;   // [128 q][64 kv] chunk-swizzled (16 KB)
  const int bx = blockIdx.x, h = blockIdx.y, spl = blockIdx.z;
  const int tid = threadIdx.x, w = tid>>6, lane = tid&63;
  const int hi = lane>>5, l31 = lane&31;
  const int qg = w>>1, kvh = w&1;   // S-phase role
  const int qh = w&1, ev = w>>1;    // PV-phase role
  const int qbase = bx*128;
  const size_t hoff = (size_t)h*N_TOK*D_DIM;
  u16* cs = spl ? cat1 : cat0;

  // Q B-frags (S-phase)
  short8 qf[16];
  {
    const u16* qp = Q + hoff + (size_t)(qbase + qg*32 + l31)*D_DIM + hi*8;
    #pragma unroll
    for (int ks = 0; ks < 16; ++ks) qf[ks] = *(const short8*)(qp + ks*16);
  }

  floatx16 o00 = {}, o01 = {}, o10 = {}, o11 = {};  // [qs][es]
  float l_lane = 0.f;

  const u16* Kb0 = Kg + hoff + (size_t)spl*2048*D_DIM;
  const u16* Vb0 = Vt + hoff + spl*2048;
  const u16* bWb = biasW + ((((size_t)(bx*4 + qg))*64 + spl*32)*64 + lane)*32 + kvh*16;

  // prologue: bias(0) + stage tile 0
  short8 bv0 = *(const short8*)(bWb);
  short8 bv1 = *(const short8*)(bWb + 8);
  {
    #pragma unroll
    for (int i = 0; i < 4; ++i){
      int ch = w*4 + i;
      int row = ch*2 + hi;
      int gch = l31 ^ (row&7);
      glds16(Kb0 + (size_t)row*D_DIM + gch*8, Ks + ch*512);
      int vrow = ch*8 + (lane>>3);
      int vgch = (lane&7) ^ (vrow&7);
      glds16(Vb0 + (size_t)vrow*N_TOK + vgch*8, Vs + ch*512);
    }
  }
  __syncthreads();

  for (int t = 0; t < 32; ++t){
    const int tn = (t + 1) & 31;

    // ---- S-phase ----
    floatx16 sa = {}, sb = {};
    const int krow = kvh*32 + l31;
    #pragma unroll
    for (int ks = 0; ks < 16; ++ks){
      int slot = (2*ks + hi) ^ (l31&7);
      short8 ka = *(const short8*)&Ks[krow*256 + slot*8];
      if (ks & 1) sb = __builtin_amdgcn_mfma_f32_32x32x16_bf16(ka, qf[ks], sb, 0, 0, 0);
      else        sa = __builtin_amdgcn_mfma_f32_32x32x16_bf16(ka, qf[ks], sa, 0, 0, 0);
    }

    // ---- softmax: p = exp2(s + bias)  (scale folded into Q, no max constant) ----
    {
      const int q = qg*32 + l31;
      #pragma unroll
      for (int g = 0; g < 4; ++g){
        u16 b0 = (g < 2) ? ((u16*)&bv0)[4*g+0] : ((u16*)&bv1)[4*(g-2)+0];
        u16 b1 = (g < 2) ? ((u16*)&bv0)[4*g+1] : ((u16*)&bv1)[4*(g-2)+1];
        u16 b2 = (g < 2) ? ((u16*)&bv0)[4*g+2] : ((u16*)&bv1)[4*(g-2)+2];
        u16 b3 = (g < 2) ? ((u16*)&bv0)[4*g+3] : ((u16*)&bv1)[4*(g-2)+3];
        float p0 = exp2f(sa[4*g+0] + sb[4*g+0] + h2f(b0));
        float p1 = exp2f(sa[4*g+1] + sb[4*g+1] + h2f(b1));
        float p2 = exp2f(sa[4*g+2] + sb[4*g+2] + h2f(b2));
        float p3 = exp2f(sa[4*g+3] + sb[4*g+3] + h2f(b3));
        l_lane += (p0 + p1) + (p2 + p3);
        uint2 pw;
        pw.x = pk2bf(p0, p1);
        pw.y = pk2bf(p2, p3);
        int slot = (kvh*4 + g) ^ (l31&7);
        *(uint2*)&Ps[q*64 + slot*8 + hi*4] = pw;
      }
    }
    __syncthreads();   // barrier 1: P visible, Ks reads done

    // stage K(t+1) + prefetch bias(t+1)
    {
      const u16* Kb = Kb0 + (size_t)tn*64*D_DIM;
      #pragma unroll
      for (int i = 0; i < 4; ++i){
        int ch = w*4 + i;
        int row = ch*2 + hi;
        int gch = l31 ^ (row&7);
        glds16(Kb + (size_t)row*D_DIM + gch*8, Ks + ch*512);
      }
      const u16* bW = bWb + (size_t)tn*64*32;
      bv0 = *(const short8*)(bW);
      bv1 = *(const short8*)(bW + 8);
    }

    // ---- PV-phase: O[q][e] ----
    #pragma unroll
    for (int ks2 = 0; ks2 < 4; ++ks2){
      int cA = ks2*2 + hi;
      int sl = cA ^ (l31&7);
      short8 pf0 = *(const short8*)&Ps[(qh*64 +      l31)*64 + sl*8];
      short8 pf1 = *(const short8*)&Ps[(qh*64 + 32 + l31)*64 + sl*8];
      short8 vf0 = *(const short8*)&Vs[(ev*64 +      l31)*64 + sl*8];
      short8 vf1 = *(const short8*)&Vs[(ev*64 + 32 + l31)*64 + sl*8];
      o00 = __builtin_amdgcn_mfma_f32_32x32x16_bf16(pf0, vf0, o00, 0, 0, 0);
      o01 = __builtin_amdgcn_mfma_f32_32x32x16_bf16(pf0, vf1, o01, 0, 0, 0);
      o10 = __builtin_amdgcn_mfma_f32_32x32x16_bf16(pf1, vf0, o10, 0, 0, 0);
      o11 = __builtin_amdgcn_mfma_f32_32x32x16_bf16(pf1, vf1, o11, 0, 0, 0);
    }
    __syncthreads();   // barrier 2: PV reads done, K(t+1) drained

    // stage V(t+1)
    {
      const u16* Vb = Vb0 + tn*64;
      #pragma unroll
      for (int i = 0; i < 4; ++i){
        int ch = w*4 + i;
        int vrow = ch*8 + (lane>>3);
        int vgch = (lane&7) ^ (vrow&7);
        glds16(Vb + (size_t)vrow*N_TOK + vgch*8, Vs + ch*512);
      }
    }
  }

  // ---- epilogue ----
  l_lane += __shfl_xor(l_lane, 32, 64);
  if (hi == 0)
    lsum4[(((size_t)spl*2 + kvh)*H_HEAD + h)*N_TOK + qbase + qg*32 + l31] = l_lane;

  #pragma unroll
  for (int reg = 0; reg < 16; ++reg){
    int qr = (reg&3) + 8*(reg>>2) + 4*hi;
    int q0 = qbase + qh*64 + qr;
    size_t c0 = (size_t)q0*(H_HEAD*D_DIM) + h*D_DIM + ev*64 + l31;
    size_t c1 = (size_t)(q0+32)*(H_HEAD*D_DIM) + h*D_DIM + ev*64 + l31;
    cs[c0]      = f2b(o00[reg]);
    cs[c0 + 32] = f2b(o01[reg]);
    cs[c1]      = f2b(o10[reg]);
    cs[c1 + 32] = f2b(o11[reg]);
  }
}

// ---------------- combine2: cat = (c0+c1) * inv_l[q,h], elementwise ----------------
__global__ void combine2(const u16* __restrict__ c0, const u16* __restrict__ c1,
                         const float* __restrict__ lsum4, u16* __restrict__ cat){
  const int q = blockIdx.x;
  const int t = threadIdx.x;
  const int col = t*8;
  const int h = t >> 5;
  float l = 0.f;
  #pragma unroll
  for (int s = 0; s < 4; ++s)
    l += lsum4[((size_t)s*H_HEAD + h)*N_TOK + q];
  float inv = (l > 0.f) ? 1.0f/l : 0.f;
  size_t base = (size_t)q*(H_HEAD*D_DIM) + col;
  short8 a = *(const short8*)(c0 + base);
  short8 b = *(const short8*)(c1 + base);
  u16 o[8];
  #pragma unroll
  for (int i = 0; i < 8; ++i)
    o[i] = f2b((b2f(((u16*)&a)[i]) + b2f(((u16*)&b)[i]))*inv);
  *(short8*)(cat + base) = *(short8*)o;
}

// ---------------- launch ----------------
extern "C" void kernel_launch(void* const* d_in, const int* in_sizes, int n_in,
                              void* d_out, int out_size, void* d_ws, size_t ws_size,
                              hipStream_t stream){
  const float* x    = (const float*)d_in[0];
  const int*   mask = (const int*)  d_in[1];
  const float* sp   = (const float*)d_in[2];
  const float* ed   = (const float*)d_in[3];
  const float* g1   = (const float*)d_in[4];
  const float* b1   = (const float*)d_in[5];
  const float* Wq   = (const float*)d_in[6];
  const float* bq   = (const float*)d_in[7];
  const float* Wk   = (const float*)d_in[8];
  const float* bk   = (const float*)d_in[9];
  const float* Wv   = (const float*)d_in[10];
  const float* bv   = (const float*)d_in[11];
  const float* Wo   = (const float*)d_in[12];
  const float* bo   = (const float*)d_in[13];
  const float* g2   = (const float*)d_in[14];
  const float* b2   = (const float*)d_in[15];
  const float* Wff  = (const float*)d_in[16];
  const float* bff  = (const float*)d_in[17];
  float* out = (float*)d_out;
  char* ws = (char*)d_ws;

  constexpr size_t MB = 1ull<<20;
  u16*   wqkv   = (u16*)  (ws + 0);                 // 3 MB
  u16*   wo_b   = (u16*)  (ws + 3*MB);              // 1 MB
  u16*   wff_b  = (u16*)  (ws + 4*MB);              // 128 KB
  float* bqkv   = (float*)(ws + 4*MB + 256*1024);   // 24 KB
  u16*   xln    = (u16*)  (ws + 4*MB + 512*1024);   // 2 MB
  float* lsum4  = (float*)(ws + 6*MB + 512*1024);   // 512 KB
  u16*   qkv    = (u16*)  (ws + 7*MB);              // 48 MB: Q@7, K@23 (V slab unused)
  u16*   vt     = (u16*)  (ws + 55*MB);             // 16 MB (written by QKV GEMM)
  u16*   biasW  = (u16*)  (ws + 71*MB);             // 32 MB
  u16*   cat0   = (u16*)  (ws + 39*MB);             // 16 MB (overlays unused V slab)
  u16*   cat1   = (u16*)  (ws + 103*MB);            // 16 MB
  u16*   cat    = (u16*)  (ws + 7*MB);              // 16 MB (overlays dead Q)
  float* pK     = (float*)(ws + 23*MB);             // 8 MB  (overlays dead K)
  float* xout   = (float*)(ws + 31*MB);             // 4 MB
  u16*   xln2   = (u16*)  (ws + 35*MB);             // 2 MB
  const size_t TS = (size_t)H_HEAD*N_TOK*D_DIM;

  // weights -> bf16, qkv bias concat
  fused_prep<<<1057, 256, 0, stream>>>(Wq, Wk, Wv, Wo, Wff, bq, bk, bv,
                                       wqkv, wo_b, wff_b, bqkv);
  // LN1
  ln_kernel<<<N_TOK, 256, 0, stream>>>(x, g1, b1, xln);

  // QKV projection (V cols written transposed straight into vt)
  gemm_bt<128,128,0><<<dim3(48, 32), 256, 0, stream>>>(xln, wqkv, 256, 256, 256,
                                                       bqkv, (const float*)vt, qkv);

  // swizzled combined bias (no constant offset, masked = -inf)
  make_biasW<<<dim3(64, 128), 256, 0, stream>>>(sp, ed, mask, biasW);

  // flash attention (prior-session baseline grid, no swizzle/setprio)
  hipFuncSetAttribute((const void*)attn_kernel,
                      hipFuncAttributeMaxDynamicSharedMemorySize, 81920);
  attn_kernel<<<dim3(32, 8, 2), 512, 81920, stream>>>(qkv, qkv + TS, vt, biasW,
                                                      cat0, cat1, lsum4);

  // combine splits + normalize (elementwise)
  combine2<<<N_TOK, 256, 0, stream>>>(cat0, cat1, lsum4, cat);

  // output projection, split-K=2, raw fp32 partials
  gemm_bt<64,64,3><<<dim3(4, 64, 2), 256, 0, stream>>>(cat, wo_b, 1024, 2048, 2048,
                                                       nullptr, nullptr, pK);

  // sum partials + bo + x residual + LN2
  ln_sum<<<N_TOK, 256, 0, stream>>>(pK, pK + (size_t)N_TOK*D_DIM, bo, x, g2, b2,
                                    xout, xln2);

  // FF + residual
  gemm_bt<64,64,2><<<dim3(4, 64), 256, 0, stream>>>(xln2, wff_b, 256, 256, 256,
                                                    bff, xout, out);
}

// Round 17
// 403.656 us; speedup vs baseline: 2.1249x; 1.0397x over previous
//
#include <hip/hip_runtime.h>
#include <hip/hip_bf16.h>
#include <hip/hip_fp16.h>
#include <string.h>

typedef unsigned short u16;
typedef __attribute__((ext_vector_type(4))) short short4v;
typedef __attribute__((ext_vector_type(8))) short short8;
typedef __attribute__((ext_vector_type(4))) float floatx4;
typedef __attribute__((ext_vector_type(16))) float floatx16;

#define N_TOK 4096
#define D_DIM 256
#define H_HEAD 8

__device__ __forceinline__ u16 f2b(float f){
  __hip_bfloat16 h = __float2bfloat16(f);
  return *reinterpret_cast<u16*>(&h);
}
__device__ __forceinline__ float b2f(u16 u){
  union { unsigned u; float f; } c; c.u = ((unsigned)u) << 16; return c.f;
}
__device__ __forceinline__ float h2f(u16 u){
  __half h; *reinterpret_cast<u16*>(&h) = u; return __half2float(h);
}
__device__ __forceinline__ u16 f2h(float f){
  __half h = __float2half(f); return *reinterpret_cast<u16*>(&h);
}
__device__ __forceinline__ unsigned pk2bf(float a, float b){
  __hip_bfloat162 h = __float22bfloat162_rn(make_float2(a, b));
  return *reinterpret_cast<unsigned*>(&h);
}

__device__ __forceinline__ void glds16(const void* g, void* l){
  __builtin_amdgcn_global_load_lds(
      (const __attribute__((address_space(1))) unsigned int*)g,
      (__attribute__((address_space(3))) unsigned int*)l, 16, 0, 0);
}

// ---------------- fused prep: weight cvt + qkv bias concat ----------------
__global__ void fused_prep(const float* __restrict__ Wq, const float* __restrict__ Wk,
                           const float* __restrict__ Wv, const float* __restrict__ Wo,
                           const float* __restrict__ Wff,
                           const float* __restrict__ bq, const float* __restrict__ bk,
                           const float* __restrict__ bv,
                           u16* __restrict__ wqkv, u16* __restrict__ wo_b,
                           u16* __restrict__ wff_b, float* __restrict__ bqkv){
  int bid = blockIdx.x;
  if (bid == 1056){
    int t = threadIdx.x;
    for (int j = 0; j < 24; ++j){
      int idx = t + j*256;
      float v;
      if (idx < 2048) v = bq[idx];
      else if (idx < 4096) v = bk[idx - 2048];
      else v = bv[idx - 4096];
      bqkv[idx] = v;
    }
    return;
  }
  const float* src; u16* dst; int base;
  if      (bid < 256) { src = Wq;  dst = wqkv;            base = bid; }
  else if (bid < 512) { src = Wk;  dst = wqkv + 524288;   base = bid - 256; }
  else if (bid < 768) { src = Wv;  dst = wqkv + 1048576;  base = bid - 512; }
  else if (bid < 1024){ src = Wo;  dst = wo_b;            base = bid - 768; }
  else                { src = Wff; dst = wff_b;           base = bid - 1024; }
  int i = (base*256 + threadIdx.x)*8;
  float4 a = *(const float4*)(src + i);
  float4 b = *(const float4*)(src + i + 4);
  u16 u[8] = {f2b(a.x),f2b(a.y),f2b(a.z),f2b(a.w),f2b(b.x),f2b(b.y),f2b(b.z),f2b(b.w)};
  *(short8*)(dst + i) = *(short8*)u;
}

// ---------------- layernorm: fp32 in -> bf16 out ----------------
__global__ void ln_kernel(const float* __restrict__ x, const float* __restrict__ g,
                          const float* __restrict__ b, u16* __restrict__ out){
  const int row = blockIdx.x;
  const int t = threadIdx.x;
  float v = x[(size_t)row*D_DIM + t];
  float s = v, ss = v*v;
  #pragma unroll
  for (int off = 32; off > 0; off >>= 1){
    s  += __shfl_down(s,  off);
    ss += __shfl_down(ss, off);
  }
  __shared__ float ls[4], lss[4];
  const int w = t >> 6, lane = t & 63;
  if (lane == 0){ ls[w] = s; lss[w] = ss; }
  __syncthreads();
  if (t == 0){
    float S  = ls[0]+ls[1]+ls[2]+ls[3];
    float SS = lss[0]+lss[1]+lss[2]+lss[3];
    float mu = S * (1.0f/D_DIM);
    float var = SS * (1.0f/D_DIM) - mu*mu;
    ls[0] = mu; lss[0] = rsqrtf(var + 1e-5f);
  }
  __syncthreads();
  float mu = ls[0], rs = lss[0];
  out[(size_t)row*D_DIM + t] = f2b((v - mu)*rs*g[t] + b[t]);
}

// ---------------- ln_sum: x_out = p0+p1+bo+x ; LN2 -> bf16 ; also write x_out fp32 ----
__global__ void ln_sum(const float* __restrict__ p0, const float* __restrict__ p1,
                       const float* __restrict__ bo, const float* __restrict__ x,
                       const float* __restrict__ g, const float* __restrict__ b,
                       float* __restrict__ xout, u16* __restrict__ xln2){
  const int row = blockIdx.x;
  const int t = threadIdx.x;
  const size_t idx = (size_t)row*D_DIM + t;
  float v = p0[idx] + p1[idx] + bo[t] + x[idx];
  float s = v, ss = v*v;
  #pragma unroll
  for (int off = 32; off > 0; off >>= 1){
    s  += __shfl_down(s,  off);
    ss += __shfl_down(ss, off);
  }
  __shared__ float ls[4], lss[4];
  const int w = t >> 6, lane = t & 63;
  if (lane == 0){ ls[w] = s; lss[w] = ss; }
  __syncthreads();
  if (t == 0){
    float S  = ls[0]+ls[1]+ls[2]+ls[3];
    float SS = lss[0]+lss[1]+lss[2]+lss[3];
    float mu = S * (1.0f/D_DIM);
    float var = SS * (1.0f/D_DIM) - mu*mu;
    ls[0] = mu; lss[0] = rsqrtf(var + 1e-5f);
  }
  __syncthreads();
  float mu = ls[0], rs = lss[0];
  xout[idx] = v;
  xln2[idx] = f2b((v - mu)*rs*g[t] + b[t]);
}

// ---------------- biasW: (spatial+edge)*log2e fp16, masked=-inf, MFMA C-layout ----
__global__ void make_biasW(const float* __restrict__ sp, const float* __restrict__ ed,
                           const int* __restrict__ mask, u16* __restrict__ out){
  __shared__ u16 bh[32][64];
  const int tg = blockIdx.x, q32 = blockIdx.y;
  const int t = threadIdx.x;
  const float L2E = 1.4426950408889634f;
  const u16 NINF = 0xFC00;  // fp16 -inf
  {
    int ql = t>>3, kc = (t&7)*8;
    size_t off = (size_t)(q32*32 + ql)*N_TOK + tg*64 + kc;
    float4 s0 = *(const float4*)(sp + off);
    float4 s1 = *(const float4*)(sp + off + 4);
    float4 e0 = *(const float4*)(ed + off);
    float4 e1 = *(const float4*)(ed + off + 4);
    int mr = mask[q32*32 + ql];
    int4 m0 = *(const int4*)(mask + tg*64 + kc);
    int4 m1 = *(const int4*)(mask + tg*64 + kc + 4);
    bh[ql][kc+0] = (mr*m0.x)==0 ? NINF : f2h((s0.x+e0.x)*L2E);
    bh[ql][kc+1] = (mr*m0.y)==0 ? NINF : f2h((s0.y+e0.y)*L2E);
    bh[ql][kc+2] = (mr*m0.z)==0 ? NINF : f2h((s0.z+e0.z)*L2E);
    bh[ql][kc+3] = (mr*m0.w)==0 ? NINF : f2h((s0.w+e0.w)*L2E);
    bh[ql][kc+4] = (mr*m1.x)==0 ? NINF : f2h((s1.x+e1.x)*L2E);
    bh[ql][kc+5] = (mr*m1.y)==0 ? NINF : f2h((s1.y+e1.y)*L2E);
    bh[ql][kc+6] = (mr*m1.z)==0 ? NINF : f2h((s1.z+e1.z)*L2E);
    bh[ql][kc+7] = (mr*m1.w)==0 ? NINF : f2h((s1.w+e1.w)*L2E);
  }
  __syncthreads();
  int lane2 = t>>2, j0 = (t&3)*8;
  u16 tmp[8];
  #pragma unroll
  for (int jj = 0; jj < 8; ++jj){
    int j = j0 + jj;
    int nb = j>>4, reg = j&15;
    int kvl = nb*32 + (reg&3) + 8*(reg>>2) + 4*(lane2>>5);
    tmp[jj] = bh[lane2&31][kvl];
  }
  u16* dst = out + (((size_t)q32*64 + tg)*64 + lane2)*32 + j0;
  *(short8*)dst = *(short8*)tmp;
}

// ---------------- bf16 GEMM, C = A * B^T (+bias, +resid), lda/ldb pitches ----
// MODE 0: QKV — out bf16; col<2048 scaled by (1/16)*log2e; cols>=4096 (V)
//         written TRANSPOSED to vt[h][e][n] (passed via `resid`).
// MODE 2: out fp32 = acc + bias[col] + resid[idx].
// MODE 3: split-K partial, out fp32 raw at Cout + z*N*D, k-offset z*K.
template<int BM, int BN, int MODE>
__launch_bounds__(256, 2)
__global__ void gemm_bt(const u16* __restrict__ A, const u16* __restrict__ B, int K,
                        int lda, int ldb,
                        const float* __restrict__ bias, const float* __restrict__ resid,
                        void* __restrict__ Cout){
  constexpr int BK = 32;
  constexpr int WM = BM/2, WN = BN/2, FM = WM/16, FN = WN/16;
  constexpr int CApW = BM/64;
  constexpr int CBpW = BN/64;
  __shared__ u16 As[BM*BK];
  __shared__ u16 Bs[BN*BK];
  const int tid = threadIdx.x, w = tid>>6, lane = tid&63;
  const int quad = lane>>4, c16 = lane&15;
  const int wr = w>>1, wc = w&1;
  const int rowT = blockIdx.y*BM, colT = blockIdx.x*BN;
  const int lr = lane>>2;
  const int spos = lane&3;
  const int koff = (MODE == 3) ? (int)blockIdx.z*K : 0;

  floatx4 acc[FM][FN] = {};

  for (int k0 = 0; k0 < K; k0 += BK){
    #pragma unroll
    for (int i = 0; i < CApW; ++i){
      int ch = w*CApW + i;
      int row = ch*16 + lr;
      int gch = spos ^ ((row>>1)&3);
      const u16* g = A + (size_t)(rowT + row)*lda + koff + k0 + gch*8;
      glds16(g, As + ch*512);
    }
    #pragma unroll
    for (int i = 0; i < CBpW; ++i){
      int ch = w*CBpW + i;
      int row = ch*16 + lr;
      int gch = spos ^ ((row>>1)&3);
      const u16* g = B + (size_t)(colT + row)*ldb + koff + k0 + gch*8;
      glds16(g, Bs + ch*512);
    }
    __syncthreads();
    short8 af[FM], bf[FN];
    #pragma unroll
    for (int i = 0; i < FM; ++i){
      int row = wr*WM + i*16 + c16;
      int slot = quad ^ ((row>>1)&3);
      af[i] = *(const short8*)&As[row*BK + slot*8];
    }
    #pragma unroll
    for (int j = 0; j < FN; ++j){
      int row = wc*WN + j*16 + c16;
      int slot = quad ^ ((row>>1)&3);
      bf[j] = *(const short8*)&Bs[row*BK + slot*8];
    }
    #pragma unroll
    for (int i = 0; i < FM; ++i)
      #pragma unroll
      for (int j = 0; j < FN; ++j)
        acc[i][j] = __builtin_amdgcn_mfma_f32_16x16x32_bf16(af[i], bf[j], acc[i][j], 0, 0, 0);
    __syncthreads();
  }

  if (MODE == 0){
    u16* o = (u16*)Cout;
    u16* vtp = (u16*)(size_t)resid;   // vt[h][e][n] destination for V cols
    #pragma unroll
    for (int i = 0; i < FM; ++i)
      #pragma unroll
      for (int j = 0; j < FN; ++j){
        int col = colT + wc*WN + j*16 + c16;
        float bv = bias[col];
        if (col < 4096){
          float sc = (col < 2048) ? 0.09016994374947424f : 1.0f;
          size_t obase = (size_t)(col>>8)*((size_t)N_TOK*D_DIM) + (col & 255);
          #pragma unroll
          for (int r = 0; r < 4; ++r){
            int row = rowT + wr*WM + i*16 + quad*4 + r;
            o[obase + (size_t)row*D_DIM] = f2b((acc[i][j][r] + bv)*sc);
          }
        } else {
          // V column -> vt[(col-4096)][n], 4 consecutive n = one 8B store
          int row0 = rowT + wr*WM + i*16 + quad*4;
          u16 o4[4];
          #pragma unroll
          for (int r = 0; r < 4; ++r) o4[r] = f2b(acc[i][j][r] + bv);
          *(short4v*)(vtp + (size_t)(col - 4096)*N_TOK + row0) = *(short4v*)o4;
        }
      }
  } else if (MODE == 2){
    float* o = (float*)Cout;
    #pragma unroll
    for (int i = 0; i < FM; ++i)
      #pragma unroll
      for (int j = 0; j < FN; ++j){
        int col = colT + wc*WN + j*16 + c16;
        float bv = bias[col];
        #pragma unroll
        for (int r = 0; r < 4; ++r){
          int row = rowT + wr*WM + i*16 + quad*4 + r;
          size_t idx = (size_t)row*D_DIM + col;
          o[idx] = acc[i][j][r] + bv + resid[idx];
        }
      }
  } else {
    float* o = (float*)Cout + (size_t)blockIdx.z*((size_t)N_TOK*D_DIM);
    #pragma unroll
    for (int i = 0; i < FM; ++i)
      #pragma unroll
      for (int j = 0; j < FN; ++j){
        int col = colT + wc*WN + j*16 + c16;
        #pragma unroll
        for (int r = 0; r < 4; ++r){
          int row = rowT + wr*WM + i*16 + quad*4 + r;
          o[(size_t)row*D_DIM + col] = acc[i][j][r];
        }
      }
  }
}

// ---------------- flash attention, single-pass over all 64 kv tiles ----------------
// R12-R17: merged the spl=0/1 kv-splits into ONE block (grid 32x8, 256
// blocks = 1/CU) iterating 64 tiles, and fused combine2's normalization
// into the epilogue: l reduced across the 2 kvh waves via LDS (reusing Ps),
// O scaled in-register, single `cat` written normalized. Eliminates the
// combine2 kernel, cat1 writes, lsum4 round-trip, and halves Q reads.
// Keeps R11's verified lessons: natural grid order (biasW L2-shared across
// h — XCD swizzle was -13%), no setprio, V LDS-staged (direct gather was
// 10x HBM). Wave roles, barriers, LDS swizzles identical to R11.
// S-phase: wave (qg=w>>1, kvh=w&1): 32kv x 32q quarter of S^T -> softmax -> P^T LDS.
// PV-phase: wave (qh=w&1, ev=w>>1): O[q 64][e 64] += P[q][kv] * V^T[kv][e].
__launch_bounds__(512, 2)
__global__ void attn_kernel(const u16* __restrict__ Q, const u16* __restrict__ Kg,
                            const u16* __restrict__ Vt, const u16* __restrict__ biasW,
                            u16* __restrict__ cat){
  extern __shared__ __align__(16) u16 lds[];
  u16* Ks = lds;           // [64 kv][256 e] chunk-swizzled (32 KB)
  u16* Vs = lds + 16384;   // [256 e][64 kv] chunk-swizzled (32 KB)
  u16* Ps = lds + 32768;   // [128 q][64 kv] chunk-swizzled (16 KB)
  const int bx = blockIdx.x, h = blockIdx.y;
  const int tid = threadIdx.x, w = tid>>6, lane = tid&63;
  const int hi = lane>>5, l31 = lane&31;
  const int qg = w>>1, kvh = w&1;   // S-phase role
  const int qh = w&1, ev = w>>1;    // PV-phase role
  const int qbase = bx*128;
  const size_t hoff = (size_t)h*N_TOK*D_DIM;

  // Q B-frags (S-phase)
  short8 qf[16];
  {
    const u16* qp = Q + hoff + (size_t)(qbase + qg*32 + l31)*D_DIM + hi*8;
    #pragma unroll
    for (int ks = 0; ks < 16; ++ks) qf[ks] = *(const short8*)(qp + ks*16);
  }

  floatx16 o00 = {}, o01 = {}, o10 = {}, o11 = {};  // [qs][es]
  float l_lane = 0.f;

  const u16* Kb0 = Kg + hoff;
  const u16* Vb0 = Vt + hoff;
  const u16* bWb = biasW + ((((size_t)(bx*4 + qg))*64)*64 + lane)*32 + kvh*16;

  // prologue: bias(0) + stage tile 0
  short8 bv0 = *(const short8*)(bWb);
  short8 bv1 = *(const short8*)(bWb + 8);
  {
    #pragma unroll
    for (int i = 0; i < 4; ++i){
      int ch = w*4 + i;
      int row = ch*2 + hi;
      int gch = l31 ^ (row&7);
      glds16(Kb0 + (size_t)row*D_DIM + gch*8, Ks + ch*512);
      int vrow = ch*8 + (lane>>3);
      int vgch = (lane&7) ^ (vrow&7);
      glds16(Vb0 + (size_t)vrow*N_TOK + vgch*8, Vs + ch*512);
    }
  }
  __syncthreads();

  for (int t = 0; t < 64; ++t){
    const int tn = t + 1;   // guarded below; never wraps

    // ---- S-phase ----
    floatx16 sa = {}, sb = {};
    const int krow = kvh*32 + l31;
    #pragma unroll
    for (int ks = 0; ks < 16; ++ks){
      int slot = (2*ks + hi) ^ (l31&7);
      short8 ka = *(const short8*)&Ks[krow*256 + slot*8];
      if (ks & 1) sb = __builtin_amdgcn_mfma_f32_32x32x16_bf16(ka, qf[ks], sb, 0, 0, 0);
      else        sa = __builtin_amdgcn_mfma_f32_32x32x16_bf16(ka, qf[ks], sa, 0, 0, 0);
    }

    // ---- softmax: p = exp2(s + bias)  (scale folded into Q, no max constant) ----
    {
      const int q = qg*32 + l31;
      #pragma unroll
      for (int g = 0; g < 4; ++g){
        u16 b0 = (g < 2) ? ((u16*)&bv0)[4*g+0] : ((u16*)&bv1)[4*(g-2)+0];
        u16 b1 = (g < 2) ? ((u16*)&bv0)[4*g+1] : ((u16*)&bv1)[4*(g-2)+1];
        u16 b2 = (g < 2) ? ((u16*)&bv0)[4*g+2] : ((u16*)&bv1)[4*(g-2)+2];
        u16 b3 = (g < 2) ? ((u16*)&bv0)[4*g+3] : ((u16*)&bv1)[4*(g-2)+3];
        float p0 = exp2f(sa[4*g+0] + sb[4*g+0] + h2f(b0));
        float p1 = exp2f(sa[4*g+1] + sb[4*g+1] + h2f(b1));
        float p2 = exp2f(sa[4*g+2] + sb[4*g+2] + h2f(b2));
        float p3 = exp2f(sa[4*g+3] + sb[4*g+3] + h2f(b3));
        l_lane += (p0 + p1) + (p2 + p3);
        uint2 pw;
        pw.x = pk2bf(p0, p1);
        pw.y = pk2bf(p2, p3);
        int slot = (kvh*4 + g) ^ (l31&7);
        *(uint2*)&Ps[q*64 + slot*8 + hi*4] = pw;
      }
    }
    __syncthreads();   // barrier 1: P visible, Ks reads done

    // stage K(t+1) + prefetch bias(t+1)
    if (t < 63){
      const u16* Kb = Kb0 + (size_t)tn*64*D_DIM;
      #pragma unroll
      for (int i = 0; i < 4; ++i){
        int ch = w*4 + i;
        int row = ch*2 + hi;
        int gch = l31 ^ (row&7);
        glds16(Kb + (size_t)row*D_DIM + gch*8, Ks + ch*512);
      }
      const u16* bW = bWb + (size_t)tn*64*32;
      bv0 = *(const short8*)(bW);
      bv1 = *(const short8*)(bW + 8);
    }

    // ---- PV-phase: O[q][e] ----
    #pragma unroll
    for (int ks2 = 0; ks2 < 4; ++ks2){
      int cA = ks2*2 + hi;
      int sl = cA ^ (l31&7);
      short8 pf0 = *(const short8*)&Ps[(qh*64 +      l31)*64 + sl*8];
      short8 pf1 = *(const short8*)&Ps[(qh*64 + 32 + l31)*64 + sl*8];
      short8 vf0 = *(const short8*)&Vs[(ev*64 +      l31)*64 + sl*8];
      short8 vf1 = *(const short8*)&Vs[(ev*64 + 32 + l31)*64 + sl*8];
      o00 = __builtin_amdgcn_mfma_f32_32x32x16_bf16(pf0, vf0, o00, 0, 0, 0);
      o01 = __builtin_amdgcn_mfma_f32_32x32x16_bf16(pf0, vf1, o01, 0, 0, 0);
      o10 = __builtin_amdgcn_mfma_f32_32x32x16_bf16(pf1, vf0, o10, 0, 0, 0);
      o11 = __builtin_amdgcn_mfma_f32_32x32x16_bf16(pf1, vf1, o11, 0, 0, 0);
    }
    __syncthreads();   // barrier 2: PV/Ps reads done, K(t+1) drained

    // stage V(t+1)
    if (t < 63){
      const u16* Vb = Vb0 + tn*64;
      #pragma unroll
      for (int i = 0; i < 4; ++i){
        int ch = w*4 + i;
        int vrow = ch*8 + (lane>>3);
        int vgch = (lane&7) ^ (vrow&7);
        glds16(Vb + (size_t)vrow*N_TOK + vgch*8, Vs + ch*512);
      }
    }
  }

  // ---- epilogue: reduce l across kvh waves (LDS in dead Ps), normalize, write ----
  l_lane += __shfl_xor(l_lane, 32, 64);   // fold hi halves: l for q = qg*32+l31
  float* lred = (float*)Ps;               // [2 kvh][128 q], 1 KB (Ps dead after barrier 2)
  if (hi == 0)
    lred[kvh*128 + qg*32 + l31] = l_lane;
  __syncthreads();

  #pragma unroll
  for (int reg = 0; reg < 16; ++reg){
    int qr = (reg&3) + 8*(reg>>2) + 4*hi;
    int q0l = qh*64 + qr;                 // local q row for o00/o01
    float la = lred[q0l]      + lred[128 + q0l];
    float lb = lred[q0l + 32] + lred[128 + q0l + 32];
    float ia = (la > 0.f) ? 1.0f/la : 0.f;
    float ib = (lb > 0.f) ? 1.0f/lb : 0.f;
    int q0 = qbase + q0l;
    size_t c0 = (size_t)q0*(H_HEAD*D_DIM) + h*D_DIM + ev*64 + l31;
    size_t c1 = (size_t)(q0+32)*(H_HEAD*D_DIM) + h*D_DIM + ev*64 + l31;
    cat[c0]      = f2b(o00[reg]*ia);
    cat[c0 + 32] = f2b(o01[reg]*ia);
    cat[c1]      = f2b(o10[reg]*ib);
    cat[c1 + 32] = f2b(o11[reg]*ib);
  }
}

// ---------------- launch ----------------
extern "C" void kernel_launch(void* const* d_in, const int* in_sizes, int n_in,
                              void* d_out, int out_size, void* d_ws, size_t ws_size,
                              hipStream_t stream){
  const float* x    = (const float*)d_in[0];
  const int*   mask = (const int*)  d_in[1];
  const float* sp   = (const float*)d_in[2];
  const float* ed   = (const float*)d_in[3];
  const float* g1   = (const float*)d_in[4];
  const float* b1   = (const float*)d_in[5];
  const float* Wq   = (const float*)d_in[6];
  const float* bq   = (const float*)d_in[7];
  const float* Wk   = (const float*)d_in[8];
  const float* bk   = (const float*)d_in[9];
  const float* Wv   = (const float*)d_in[10];
  const float* bv   = (const float*)d_in[11];
  const float* Wo   = (const float*)d_in[12];
  const float* bo   = (const float*)d_in[13];
  const float* g2   = (const float*)d_in[14];
  const float* b2   = (const float*)d_in[15];
  const float* Wff  = (const float*)d_in[16];
  const float* bff  = (const float*)d_in[17];
  float* out = (float*)d_out;
  char* ws = (char*)d_ws;

  constexpr size_t MB = 1ull<<20;
  u16*   wqkv   = (u16*)  (ws + 0);                 // 3 MB
  u16*   wo_b   = (u16*)  (ws + 3*MB);              // 1 MB
  u16*   wff_b  = (u16*)  (ws + 4*MB);              // 128 KB
  float* bqkv   = (float*)(ws + 4*MB + 256*1024);   // 24 KB
  u16*   xln    = (u16*)  (ws + 4*MB + 512*1024);   // 2 MB
  u16*   qkv    = (u16*)  (ws + 7*MB);              // 48 MB: Q@7, K@23 (V slab unused)
  u16*   vt     = (u16*)  (ws + 55*MB);             // 16 MB (written by QKV GEMM)
  u16*   biasW  = (u16*)  (ws + 71*MB);             // 32 MB
  u16*   cat    = (u16*)  (ws + 103*MB);            // 16 MB (disjoint from live bufs)
  float* pK     = (float*)(ws + 23*MB);             // 8 MB  (overlays dead K)
  float* xout   = (float*)(ws + 31*MB);             // 4 MB
  u16*   xln2   = (u16*)  (ws + 35*MB);             // 2 MB
  const size_t TS = (size_t)H_HEAD*N_TOK*D_DIM;

  // weights -> bf16, qkv bias concat
  fused_prep<<<1057, 256, 0, stream>>>(Wq, Wk, Wv, Wo, Wff, bq, bk, bv,
                                       wqkv, wo_b, wff_b, bqkv);
  // LN1
  ln_kernel<<<N_TOK, 256, 0, stream>>>(x, g1, b1, xln);

  // QKV projection (V cols written transposed straight into vt)
  gemm_bt<128,128,0><<<dim3(48, 32), 256, 0, stream>>>(xln, wqkv, 256, 256, 256,
                                                       bqkv, (const float*)vt, qkv);

  // swizzled combined bias (no constant offset, masked = -inf)
  make_biasW<<<dim3(64, 128), 256, 0, stream>>>(sp, ed, mask, biasW);

  // flash attention (single-pass 64 tiles, natural grid, fused normalize)
  hipFuncSetAttribute((const void*)attn_kernel,
                      hipFuncAttributeMaxDynamicSharedMemorySize, 81920);
  attn_kernel<<<dim3(32, 8), 512, 81920, stream>>>(qkv, qkv + TS, vt, biasW, cat);

  // output projection, split-K=2, raw fp32 partials
  gemm_bt<64,64,3><<<dim3(4, 64, 2), 256, 0, stream>>>(cat, wo_b, 1024, 2048, 2048,
                                                       nullptr, nullptr, pK);

  // sum partials + bo + x residual + LN2
  ln_sum<<<N_TOK, 256, 0, stream>>>(pK, pK + (size_t)N_TOK*D_DIM, bo, x, g2, b2,
                                    xout, xln2);

  // FF + residual
  gemm_bt<64,64,2><<<dim3(4, 64), 256, 0, stream>>>(xln2, wff_b, 256, 256, 256,
                                                    bff, xout, out);
}